// Round 12
// baseline (329.218 us; speedup 1.0000x reference)
//
#include <hip/hip_runtime.h>

#define S_LEN 1024
#define HID   4544            // 71*64; K of both GEMMs
#define NH    71
#define NQKV  4672            // 73*64
#define NQKV_PAD 4736         // 37*128
#define ND_PAD   4608         // 36*128

typedef __attribute__((ext_vector_type(4)))  float f32x4;
typedef __attribute__((ext_vector_type(16))) float f32x16;
typedef __attribute__((ext_vector_type(4))) unsigned short u16x4;
typedef __attribute__((ext_vector_type(8))) unsigned short u16x8;
typedef __attribute__((ext_vector_type(8))) __bf16 bf16x8;

__device__ __forceinline__ bf16x8 as_bf(u16x8 v) { return __builtin_bit_cast(bf16x8, v); }

__device__ __forceinline__ unsigned short f2bf(float f) {
    unsigned u = __builtin_bit_cast(unsigned, f);
    return (unsigned short)((u + 0x7FFFu + ((u >> 16) & 1u)) >> 16);  // RNE
}
__device__ __forceinline__ float bf2f(unsigned short u) {
    return __builtin_bit_cast(float, (unsigned)u << 16);
}
__device__ __forceinline__ unsigned pk2(float a, float b) {   // packed bf16x2, RNE
    return (unsigned)f2bf(a) | ((unsigned)f2bf(b) << 16);
}
__device__ __forceinline__ void gload16(const void* g, void* l) {
    __builtin_amdgcn_global_load_lds((const __attribute__((address_space(1))) unsigned int*)g,
                                     (__attribute__((address_space(3))) unsigned int*)l,
                                     16, 0, 0);
}

// ---------- fp32 -> bf16 elementwise (x) ----------
__global__ __launch_bounds__(256) void cvt_x_kernel(const float4* __restrict__ x,
                                                    ushort4* __restrict__ y) {
    int i = blockIdx.x * 256 + threadIdx.x;
    float4 v = x[i];
    ushort4 r;
    r.x = f2bf(v.x); r.y = f2bf(v.y); r.z = f2bf(v.z); r.w = f2bf(v.w);
    y[i] = r;
}

// ---------- fp32 (K x N) -> bf16 transposed (Npad x K); zero-pad n >= N ----------
__global__ __launch_bounds__(256) void cvt_wT_kernel(const float* __restrict__ w,
                                                     unsigned short* __restrict__ wt,
                                                     int K, int N) {
    __shared__ float t[64][65];
    int n0 = blockIdx.x * 64, k0 = blockIdx.y * 64;
    int tx = threadIdx.x & 15, ty = threadIdx.x >> 4;   // 16 x 16
#pragma unroll
    for (int r = 0; r < 64; r += 16) {
        int k = k0 + ty + r;
        int n = n0 + tx * 4;
        float4 v = make_float4(0.f, 0.f, 0.f, 0.f);
        if (n < N) v = *(const float4*)&w[(size_t)k * N + n];   // N % 4 == 0
        t[ty + r][tx * 4 + 0] = v.x;
        t[ty + r][tx * 4 + 1] = v.y;
        t[ty + r][tx * 4 + 2] = v.z;
        t[ty + r][tx * 4 + 3] = v.w;
    }
    __syncthreads();
    int nr = threadIdx.x >> 2;           // output row n (0..63)
    int kq = (threadIdx.x & 3) * 16;     // 16 k-values per thread
    unsigned short tmp[16];
#pragma unroll
    for (int z = 0; z < 16; z++) tmp[z] = f2bf(t[kq + z][nr]);
    u16x8* dst = (u16x8*)&wt[(size_t)(n0 + nr) * K + k0 + kq];
    dst[0] = *(const u16x8*)&tmp[0];
    dst[1] = *(const u16x8*)&tmp[8];
}

// ---------- RoPE cos/sin table: [1024][32] fp32 each ----------
__global__ void rope_table_kernel(float* __restrict__ cs, float* __restrict__ sn) {
    int s = blockIdx.x, i = threadIdx.x;     // 32 threads
    float inv = powf(10000.0f, -(2.0f * (float)i) / 64.0f);
    float f = (float)s * inv;
    cs[s * 32 + i] = cosf(f);
    sn[s * 32 + i] = sinf(f);
}

// ---------- bf16 MFMA GEMM, 32x32x16 frags, BM=128 BN=128 BK=32 ----------
// 4 waves (2x2), wave = 64x64 = 2x2 frags of 32x32. Per wave-step: 8
// ds_read_b128 + 8 MFMA for 0.26 MFLOP -> 30.5 read-insts/MFLOP (r7: 45.8).
// LDS 32KB total -> 4 blocks/CU (16 waves/CU). Depth-2 counted-vmcnt(4),
// chunked XCD map, r7-style both-sides swizzle (c4 ^ (row&3)).
// C/D layout (HW-verified r11): col=lane&31, row=(r&3)+8*(r>>2)+4*(lane>>5).
// EPI 0: C fp32 (guard col<n_store). EPI 1: QKV epilogue (head = 2*nb + wn;
// ni = d-half): rope q (x1/8) / rope k / v transposed / skip head 73 (pad).
template<int EPI>
__global__ __launch_bounds__(256, 4) void gemm_bt_kernel(
        const unsigned short* __restrict__ A, const unsigned short* __restrict__ BT,
        void* __restrict__ Cout, const float* __restrict__ cs_t,
        const float* __restrict__ sn_t, unsigned short* __restrict__ k_out,
        unsigned short* __restrict__ v_out, int K, int ldc, int n_store) {
    __shared__ unsigned short As[2][128 * 32];   // 8KB each
    __shared__ unsigned short Bs[2][128 * 32];   // 8KB each
    int p = blockIdx.x;
    int per = gridDim.x >> 3;                    // blocks per XCD chunk
    int l = (p & 7) * per + (p >> 3);
    int m0 = (l & 7) * 128;
    int nb = l >> 3;
    int n0 = nb * 128;
    int t = threadIdx.x;
    int wv = t >> 6, lane = t & 63;
    int wm = wv >> 1, wn = wv & 1;
    int lrow = lane & 31, lk = lane >> 5;

    f32x16 acc[2][2];
#pragma unroll
    for (int mi = 0; mi < 2; mi++)
#pragma unroll
        for (int ni = 0; ni < 2; ni++) acc[mi][ni] = (f32x16)0.0f;

    const char* Ab = (const char*)A;
    const char* Bb = (const char*)BT;
    size_t rs = (size_t)K * 2;

    auto stage = [&](int step, int buf) {        // 4 gload16 per thread
        size_t kb = (size_t)step * 64;           // 32 elems * 2B
#pragma unroll
        for (int i = 0; i < 2; i++) {            // A: 512 chunks of 16B
            int chunk = i * 256 + t;
            int row = chunk >> 2, c4 = chunk & 3;
            int csrc = c4 ^ (row & 3);
            gload16(Ab + (size_t)(m0 + row) * rs + kb + csrc * 16,
                    (char*)As[buf] + chunk * 16);
        }
#pragma unroll
        for (int i = 0; i < 2; i++) {            // B: 512 chunks
            int chunk = i * 256 + t;
            int row = chunk >> 2, c4 = chunk & 3;
            int csrc = c4 ^ (row & 3);
            gload16(Bb + (size_t)(n0 + row) * rs + kb + csrc * 16,
                    (char*)Bs[buf] + chunk * 16);
        }
    };

    int nsteps = K >> 5;                         // 142
    stage(0, 0);
    if (nsteps > 1) stage(1, 1);
    for (int s = 0; s < nsteps; ++s) {
        int cur = s & 1;
        if (s + 1 < nsteps) { asm volatile("s_waitcnt vmcnt(4)" ::: "memory"); }
        else                { asm volatile("s_waitcnt vmcnt(0)" ::: "memory"); }
        __builtin_amdgcn_s_barrier();            // stage(s) fully landed (all waves)
        bf16x8 af[2][2], bfr[2][2];
#pragma unroll
        for (int mi = 0; mi < 2; mi++) {
            int row = wm * 64 + mi * 32 + lrow;
#pragma unroll
            for (int kk = 0; kk < 2; kk++)
                af[mi][kk] = as_bf(*(const u16x8*)&As[cur][row * 32 + (((kk * 2 + lk) ^ (row & 3)) << 3)]);
        }
#pragma unroll
        for (int ni = 0; ni < 2; ni++) {
            int row = wn * 64 + ni * 32 + lrow;
#pragma unroll
            for (int kk = 0; kk < 2; kk++)
                bfr[ni][kk] = as_bf(*(const u16x8*)&Bs[cur][row * 32 + (((kk * 2 + lk) ^ (row & 3)) << 3)]);
        }
        asm volatile("s_waitcnt lgkmcnt(0)" ::: "memory");   // frags in regs
        __builtin_amdgcn_s_barrier();            // all waves done reading buf cur
        if (s + 2 < nsteps) stage(s + 2, cur);   // loads fly under the MFMAs
#pragma unroll
        for (int kk = 0; kk < 2; kk++)
#pragma unroll
            for (int mi = 0; mi < 2; mi++)
#pragma unroll
                for (int ni = 0; ni < 2; ni++)
                    acc[mi][ni] = __builtin_amdgcn_mfma_f32_32x32x16_bf16(
                        af[mi][kk], bfr[ni][kk], acc[mi][ni], 0, 0, 0);
    }

    if (EPI == 0) {
        float* C = (float*)Cout;
#pragma unroll
        for (int mi = 0; mi < 2; mi++)
#pragma unroll
            for (int ni = 0; ni < 2; ni++) {
                int col = n0 + wn * 64 + ni * 32 + lrow;
                if (col < n_store) {
#pragma unroll
                    for (int r = 0; r < 16; r++) {
                        int row = m0 + wm * 64 + mi * 32 + (r & 3) + 8 * (r >> 2) + 4 * lk;
                        C[(size_t)row * ldc + col] = acc[mi][ni][r];
                    }
                }
            }
    } else {
        int hh = nb * 2 + wn;                 // head index (0..73)
        if (hh == 72) {                       // v: write transposed [d][1024]
#pragma unroll
            for (int mi = 0; mi < 2; mi++)
#pragma unroll
                for (int ni = 0; ni < 2; ni++) {
                    int d = ni * 32 + lrow;
#pragma unroll
                    for (int g = 0; g < 4; g++) {
                        int s0 = m0 + wm * 64 + mi * 32 + 8 * g + 4 * lk;
                        u16x4 pk;
#pragma unroll
                        for (int i = 0; i < 4; i++) pk[i] = f2bf(acc[mi][ni][g * 4 + i]);
                        *(u16x4*)&v_out[(size_t)d * S_LEN + s0] = pk;
                    }
                }
        } else if (hh < 72) {                 // q (hh<71) / k (hh==71): rope
            unsigned short* qb = (unsigned short*)Cout;
            float qscale = (hh < 71) ? 0.125f : 1.0f;
#pragma unroll
            for (int mi = 0; mi < 2; mi++)
#pragma unroll
                for (int r = 0; r < 16; r++) {
                    int s = m0 + wm * 64 + mi * 32 + (r & 3) + 8 * (r >> 2) + 4 * lk;
                    float c = cs_t[s * 32 + lrow];
                    float g = sn_t[s * 32 + lrow];
                    float x0 = acc[mi][0][r];          // d = lrow (< 32)
                    float x1 = acc[mi][1][r];          // d = lrow + 32
                    float r0 = (x0 * c - x1 * g) * qscale;
                    float r1 = (x1 * c + x0 * g) * qscale;
                    if (hh < 71) {
                        qb[(size_t)s * HID + hh * 64 + lrow]      = f2bf(r0);
                        qb[(size_t)s * HID + hh * 64 + 32 + lrow] = f2bf(r1);
                    } else {
                        k_out[(size_t)s * 64 + lrow]      = f2bf(r0);
                        k_out[(size_t)s * 64 + 32 + lrow] = f2bf(r1);
                    }
                }
        }                                     // hh == 73: padding, skip
    }
}

// ---------- flash attention (MQA), split-K, LDS-shared K/V, counted-vmcnt ----------
// grid (40, 71), block 256. Block = (head, chunk c, 4 q-tiles j0..j0+3).
__global__ __launch_bounds__(256, 3) void attn_kernel(
        const unsigned short* __restrict__ qb, const unsigned short* __restrict__ kr,
        const unsigned short* __restrict__ vt, unsigned short* __restrict__ ctx,
        unsigned short* __restrict__ Opart, float2* __restrict__ MLpart) {
    __shared__ unsigned short Ks[2][64 * 64];
    __shared__ unsigned short Vs[2][64 * 64];
    __shared__ unsigned short Pl[4][16 * 72];
    int h = blockIdx.y;
    int u = blockIdx.x;
    int c, j0;
    if (u < 16)      { c = 0; j0 = u * 4; }
    else if (u < 28) { c = 1; j0 = 16 + (u - 16) * 4; }
    else if (u < 36) { c = 2; j0 = 32 + (u - 28) * 4; }
    else             { c = 3; j0 = 48 + (u - 36) * 4; }
    int t = threadIdx.x, wv = t >> 6, lane = t & 63, lr = lane & 15, lg = lane >> 4;
    int j = j0 + wv;
    int qs = j * 16 + lr;
    int k_lo = c * 256;
    int kend_w   = min((j + 1) * 16, k_lo + 256);
    int kend_max = min((j0 + 4) * 16, k_lo + 256);
    int nt = (kend_max - k_lo) >> 6;
    int nch = (j >> 4) + 1;
    int srow = t >> 3, sc16 = t & 7, sw = lr & 7;

    auto stage = [&](int ti, int buf) {          // 4 global_load_lds per thread
        size_t kbase = (size_t)(k_lo + ti * 64);
#pragma unroll
        for (int i = 0; i < 2; i++) {
            int row = i * 32 + srow;
            int csrc = sc16 ^ (row & 7);
            gload16((const char*)kr + (kbase + row) * 128 + csrc * 16,
                    (char*)Ks[buf] + (i * 256 + t) * 16);
        }
#pragma unroll
        for (int i = 0; i < 2; i++) {
            int row = i * 32 + srow;
            int csrc = sc16 ^ (row & 7);
            gload16((const char*)vt + (size_t)row * 2048 + kbase * 2 + csrc * 16,
                    (char*)Vs[buf] + (i * 256 + t) * 16);
        }
    };

    bf16x8 qf[2];
#pragma unroll
    for (int dc = 0; dc < 2; dc++)
        qf[dc] = as_bf(*(const u16x8*)&qb[(size_t)qs * HID + h * 64 + dc * 32 + 8 * lg]);

    float m_i = -1e30f, l_i = 0.0f;
    f32x4 o[4];
#pragma unroll
    for (int d4 = 0; d4 < 4; d4++) o[d4] = (f32x4)0.0f;

    stage(0, 0);
    if (nt > 1) stage(1, 1);

    for (int ti = 0; ti < nt; ti++) {
        int cur = ti & 1;
        if (ti + 1 < nt) { asm volatile("s_waitcnt vmcnt(4)" ::: "memory"); }
        else             { asm volatile("s_waitcnt vmcnt(0)" ::: "memory"); }
        __builtin_amdgcn_s_barrier();            // tile ti fully landed
        int k0 = k_lo + ti * 64;
        if (k0 < kend_w) {
            f32x4 st[4];
#pragma unroll
            for (int nc = 0; nc < 4; nc++) st[nc] = (f32x4)0.0f;
#pragma unroll
            for (int nc = 0; nc < 4; nc++) {
                int krow = nc * 16 + lr;
#pragma unroll
                for (int dc = 0; dc < 2; dc++) {
                    bf16x8 kf = as_bf(*(const u16x8*)&Ks[cur][krow * 64 + (((dc * 4 + lg) ^ sw) << 3)]);
                    st[nc] = __builtin_amdgcn_mfma_f32_16x16x32_bf16(kf, qf[dc], st[nc], 0, 0, 0);
                }
            }
            bool needmask = (k0 + 64 > j * 16);
            float mx = -1e30f;
            if (needmask) {
#pragma unroll
                for (int nc = 0; nc < 4; nc++)
#pragma unroll
                    for (int i = 0; i < 4; i++) {
                        int ks = k0 + nc * 16 + 4 * lg + i;
                        float v = (ks <= qs) ? st[nc][i] : -1e30f;
                        st[nc][i] = v;
                        mx = fmaxf(mx, v);
                    }
            } else {
#pragma unroll
                for (int nc = 0; nc < 4; nc++)
#pragma unroll
                    for (int i = 0; i < 4; i++) mx = fmaxf(mx, st[nc][i]);
            }
            mx = fmaxf(mx, __shfl_xor(mx, 16));
            mx = fmaxf(mx, __shfl_xor(mx, 32));
            // T13 defer-max: skip rescale while max grows by <= 8
            if (!__all(mx <= m_i + 8.0f)) {
                float mn = fmaxf(m_i, mx);
                float so = __expf(m_i - mn);
                l_i *= so;
#pragma unroll
                for (int d4 = 0; d4 < 4; d4++)
#pragma unroll
                    for (int i = 0; i < 4; i++) o[d4][i] *= so;
                m_i = mn;
            }
            float ps = 0.0f;
#pragma unroll
            for (int nc = 0; nc < 4; nc++)
#pragma unroll
                for (int i = 0; i < 4; i++) {
                    float v = st[nc][i];
                    float e = (!needmask || v > -1e29f) ? __expf(v - m_i) : 0.0f;
                    st[nc][i] = e;
                    ps += e;
                }
            ps += __shfl_xor(ps, 16);
            ps += __shfl_xor(ps, 32);
            l_i += ps;
            // P^T (lane-local) -> Pl[q=lr][k] (pad 72: conflict-free)
#pragma unroll
            for (int nc = 0; nc < 4; nc++) {
                *(unsigned*)&Pl[wv][lr * 72 + nc * 16 + 4 * lg]     = pk2(st[nc][0], st[nc][1]);
                *(unsigned*)&Pl[wv][lr * 72 + nc * 16 + 4 * lg + 2] = pk2(st[nc][2], st[nc][3]);
            }
            bf16x8 pb[2];
#pragma unroll
            for (int kk = 0; kk < 2; kk++)
                pb[kk] = as_bf(*(const u16x8*)&Pl[wv][lr * 72 + kk * 32 + 8 * lg]);
#pragma unroll
            for (int d4 = 0; d4 < 4; d4++) {
                int vrow = d4 * 16 + lr;
#pragma unroll
                for (int kk = 0; kk < 2; kk++) {
                    bf16x8 vf = as_bf(*(const u16x8*)&Vs[cur][vrow * 64 + (((kk * 4 + lg) ^ sw) << 3)]);
                    o[d4] = __builtin_amdgcn_mfma_f32_16x16x32_bf16(vf, pb[kk], o[d4], 0, 0, 0);
                }
            }
        }
        __builtin_amdgcn_s_barrier();            // all waves consumed buf cur
        if (ti + 2 < nt) stage(ti + 2, cur);     // overwrite buf cur
    }

    if (nch == 1) {
        float linv = 1.0f / l_i;
#pragma unroll
        for (int d4 = 0; d4 < 4; d4++) {
            u16x4 pk;
#pragma unroll
            for (int i = 0; i < 4; i++) pk[i] = f2bf(o[d4][i] * linv);
            *(u16x4*)&ctx[(size_t)qs * HID + h * 64 + d4 * 16 + 4 * lg] = pk;
        }
    } else {
        int pi = (h * 48 + (j - 16)) * 4 + c;
#pragma unroll
        for (int d4 = 0; d4 < 4; d4++) {
            u16x4 pk;
#pragma unroll
            for (int i = 0; i < 4; i++) pk[i] = f2bf(o[d4][i]);
            *(u16x4*)&Opart[(size_t)pi * 1024 + lr * 64 + d4 * 16 + 4 * lg] = pk;
        }
        if (lg == 0) MLpart[pi * 16 + lr] = make_float2(m_i, l_i);
    }
}

// ---------- split-K merge: one wave per (h, j>=16) ----------
__global__ __launch_bounds__(256) void merge_kernel(
        const unsigned short* __restrict__ Opart, const float2* __restrict__ MLpart,
        unsigned short* __restrict__ ctx) {
    int mu = blockIdx.x * 4 + (threadIdx.x >> 6);
    int lane = threadIdx.x & 63;
    int h = mu / 48, jj = mu % 48, j = 16 + jj;
    int nch = (j >> 4) + 1;
    int base = (h * 48 + jj) * 4;
    for (int q = 0; q < 16; q++) {
        float m[4], l[4], w[4];
        float M = -1e30f;
        for (int c = 0; c < nch; c++) {
            float2 ml = MLpart[(base + c) * 16 + q];
            m[c] = ml.x; l[c] = ml.y;
            M = fmaxf(M, m[c]);
        }
        float L = 0.0f;
        for (int c = 0; c < nch; c++) { w[c] = __expf(m[c] - M); L += l[c] * w[c]; }
        float acc = 0.0f;
        for (int c = 0; c < nch; c++)
            acc += w[c] * bf2f(Opart[(size_t)(base + c) * 1024 + q * 64 + lane]);
        ctx[(size_t)(j * 16 + q) * HID + h * 64 + lane] = f2bf(acc / L);
    }
}

extern "C" void kernel_launch(void* const* d_in, const int* in_sizes, int n_in,
                              void* d_out, int out_size, void* d_ws, size_t ws_size,
                              hipStream_t stream) {
    const float* hs      = (const float*)d_in[0];
    // d_in[1] = attention_mask (analytic causal mask used instead)
    const float* qkv_w   = (const float*)d_in[2];
    const float* dense_w = (const float*)d_in[3];
    float* out = (float*)d_out;

    char* ws = (char*)d_ws;
    size_t off = 0;
    auto alloc = [&](size_t bytes) -> void* {
        void* p = ws + off;
        off += (bytes + 255) & ~(size_t)255;
        return p;
    };
    unsigned short* x_bf   = (unsigned short*)alloc((size_t)S_LEN * HID * 2);      // 9.3 MB
    unsigned short* wqkvT  = (unsigned short*)alloc((size_t)NQKV_PAD * HID * 2);   // 43.0 MB
    unsigned short* q_bf   = (unsigned short*)alloc((size_t)S_LEN * HID * 2);      // 9.3 MB
    unsigned short* k_rope = (unsigned short*)alloc((size_t)S_LEN * 64 * 2);
    unsigned short* v_t    = (unsigned short*)alloc((size_t)64 * S_LEN * 2);
    unsigned short* ctx    = (unsigned short*)alloc((size_t)S_LEN * HID * 2);      // 9.3 MB
    unsigned short* wdT    = (unsigned short*)alloc((size_t)ND_PAD * HID * 2);     // 41.9 MB
    float*          cs_t   = (float*)alloc((size_t)S_LEN * 32 * 4);
    float*          sn_t   = (float*)alloc((size_t)S_LEN * 32 * 4);
    (void)ws_size;   // ~113 MB
    // Opart/MLpart alias wqkvT (dead after QKV GEMM; attn/merge run later)
    unsigned short* Opart  = wqkvT;                                   // 27.9 MB
    float2*         MLpart = (float2*)((char*)wqkvT + (size_t)71 * 48 * 4 * 1024 * 2);

    cvt_x_kernel<<<dim3(S_LEN * HID / 1024), dim3(256), 0, stream>>>(
        (const float4*)hs, (ushort4*)x_bf);
    cvt_wT_kernel<<<dim3(NQKV_PAD / 64, HID / 64), dim3(256), 0, stream>>>(
        qkv_w, wqkvT, HID, NQKV);
    cvt_wT_kernel<<<dim3(ND_PAD / 64, HID / 64), dim3(256), 0, stream>>>(
        dense_w, wdT, HID, HID);
    rope_table_kernel<<<dim3(S_LEN), dim3(32), 0, stream>>>(cs_t, sn_t);

    // QKV GEMM + fused extract/RoPE epilogue (296 = 8 XCD-chunks of 37)
    gemm_bt_kernel<1><<<dim3(NQKV_PAD / 128 * 8), dim3(256), 0, stream>>>(
        x_bf, wqkvT, q_bf, cs_t, sn_t, k_rope, v_t, HID, HID, NQKV);

    attn_kernel<<<dim3(40, NH), dim3(256), 0, stream>>>(
        q_bf, k_rope, v_t, ctx, Opart, MLpart);

    merge_kernel<<<dim3(NH * 48 / 4), dim3(256), 0, stream>>>(Opart, MLpart, ctx);

    // dense GEMM (288 = 8 XCD-chunks of 36)
    gemm_bt_kernel<0><<<dim3(ND_PAD / 128 * 8), dim3(256), 0, stream>>>(
        ctx, wdT, out, nullptr, nullptr, nullptr, nullptr, HID, HID, HID);
}

// Round 13
// 259.172 us; speedup vs baseline: 1.2703x; 1.2703x over previous
//
#include <hip/hip_runtime.h>

#define S_LEN 1024
#define HID   4544            // 71*64; K of both GEMMs
#define NH    71
#define NQKV  4672            // 73*64
#define NQKV_PAD 4736         // 37*128
#define ND_PAD   4608         // 36*128

typedef __attribute__((ext_vector_type(4)))  float f32x4;
typedef __attribute__((ext_vector_type(4))) unsigned short u16x4;
typedef __attribute__((ext_vector_type(8))) unsigned short u16x8;
typedef __attribute__((ext_vector_type(8))) __bf16 bf16x8;

__device__ __forceinline__ bf16x8 as_bf(u16x8 v) { return __builtin_bit_cast(bf16x8, v); }

__device__ __forceinline__ unsigned short f2bf(float f) {
    unsigned u = __builtin_bit_cast(unsigned, f);
    return (unsigned short)((u + 0x7FFFu + ((u >> 16) & 1u)) >> 16);  // RNE
}
__device__ __forceinline__ float bf2f(unsigned short u) {
    return __builtin_bit_cast(float, (unsigned)u << 16);
}
__device__ __forceinline__ unsigned pk2(float a, float b) {   // packed bf16x2, RNE
    return (unsigned)f2bf(a) | ((unsigned)f2bf(b) << 16);
}
__device__ __forceinline__ void gload16(const void* g, void* l) {
    __builtin_amdgcn_global_load_lds((const __attribute__((address_space(1))) unsigned int*)g,
                                     (__attribute__((address_space(3))) unsigned int*)l,
                                     16, 0, 0);
}

// ---------- fp32 -> bf16 elementwise (x) ----------
__global__ __launch_bounds__(256) void cvt_x_kernel(const float4* __restrict__ x,
                                                    ushort4* __restrict__ y) {
    int i = blockIdx.x * 256 + threadIdx.x;
    float4 v = x[i];
    ushort4 r;
    r.x = f2bf(v.x); r.y = f2bf(v.y); r.z = f2bf(v.z); r.w = f2bf(v.w);
    y[i] = r;
}

// ---------- fp32 (K x N) -> bf16 transposed (Npad x K); zero-pad n >= N ----------
__global__ __launch_bounds__(256) void cvt_wT_kernel(const float* __restrict__ w,
                                                     unsigned short* __restrict__ wt,
                                                     int K, int N) {
    __shared__ float t[64][65];
    int n0 = blockIdx.x * 64, k0 = blockIdx.y * 64;
    int tx = threadIdx.x & 15, ty = threadIdx.x >> 4;   // 16 x 16
#pragma unroll
    for (int r = 0; r < 64; r += 16) {
        int k = k0 + ty + r;
        int n = n0 + tx * 4;
        float4 v = make_float4(0.f, 0.f, 0.f, 0.f);
        if (n < N) v = *(const float4*)&w[(size_t)k * N + n];   // N % 4 == 0
        t[ty + r][tx * 4 + 0] = v.x;
        t[ty + r][tx * 4 + 1] = v.y;
        t[ty + r][tx * 4 + 2] = v.z;
        t[ty + r][tx * 4 + 3] = v.w;
    }
    __syncthreads();
    int nr = threadIdx.x >> 2;           // output row n (0..63)
    int kq = (threadIdx.x & 3) * 16;     // 16 k-values per thread
    unsigned short tmp[16];
#pragma unroll
    for (int z = 0; z < 16; z++) tmp[z] = f2bf(t[kq + z][nr]);
    u16x8* dst = (u16x8*)&wt[(size_t)(n0 + nr) * K + k0 + kq];
    dst[0] = *(const u16x8*)&tmp[0];
    dst[1] = *(const u16x8*)&tmp[8];
}

// ---------- RoPE cos/sin table: [1024][32] fp32 each ----------
__global__ void rope_table_kernel(float* __restrict__ cs, float* __restrict__ sn) {
    int s = blockIdx.x, i = threadIdx.x;     // 32 threads
    float inv = powf(10000.0f, -(2.0f * (float)i) / 64.0f);
    float f = (float)s * inv;
    cs[s * 32 + i] = cosf(f);
    sn[s * 32 + i] = sinf(f);
}

// ---------- bf16 MFMA GEMM: BM=64 BN=128 BK=64, 2 waves, wave = 64x64 ----------
// 16x16x32 frags, 4x4 per wave. Per wave-step: 16 ds_read_b128 + 32 MFMA =
// 30.5 read-insts/MFLOP (r7 structure: 45.8) — attacks the measured LDS-issue
// wall. Row/swizzle/staging pattern BYTE-IDENTICAL to r7 (the only verified
// conflict-free one: 128B rows, slot=(kk*4+lg)^(row&7)). LDS 48KB -> 3
// blocks/CU. Depth-2 counted vmcnt(12). Chunked XCD map, m-fastest.
// EPI 0: C fp32 (guard col < n_store). EPI 1: QKV epilogue, head = 2*nb+wn.
template<int EPI>
__global__ __launch_bounds__(128, 2) void gemm_bt_kernel(
        const unsigned short* __restrict__ A, const unsigned short* __restrict__ BT,
        void* __restrict__ Cout, const float* __restrict__ cs_t,
        const float* __restrict__ sn_t, unsigned short* __restrict__ k_out,
        unsigned short* __restrict__ v_out, int K, int ldc, int n_store) {
    __shared__ unsigned short As[2][64 * 64];    // 8KB each
    __shared__ unsigned short Bs[2][128 * 64];   // 16KB each
    int p = blockIdx.x;
    int per = gridDim.x >> 3;                    // blocks per XCD chunk
    int l = (p & 7) * per + (p >> 3);
    int msl = l & 15, nb = l >> 4;
    int m0 = msl * 64, n0 = nb * 128;
    int t = threadIdx.x;                         // 0..127
    int wn = t >> 6;                             // wave = n-half
    int lane = t & 63, lr = lane & 15, lg = lane >> 4;

    f32x4 acc[4][4];
#pragma unroll
    for (int mi = 0; mi < 4; mi++)
#pragma unroll
        for (int ni = 0; ni < 4; ni++) acc[mi][ni] = (f32x4)0.0f;

    const char* Ab = (const char*)A;
    const char* Bb = (const char*)BT;
    size_t rs = (size_t)K * 2;

    auto stage = [&](int step, int buf) {        // 12 gload16 per thread
        size_t kb = (size_t)step * 128;          // 64 elems * 2B
#pragma unroll
        for (int i = 0; i < 4; i++) {            // A: 512 chunks of 16B
            int chunk = i * 128 + t;
            int row = chunk >> 3, c8 = chunk & 7;
            int csrc = c8 ^ (row & 7);
            gload16(Ab + (size_t)(m0 + row) * rs + kb + csrc * 16,
                    (char*)As[buf] + chunk * 16);
        }
#pragma unroll
        for (int i = 0; i < 8; i++) {            // B: 1024 chunks
            int chunk = i * 128 + t;
            int row = chunk >> 3, c8 = chunk & 7;
            int csrc = c8 ^ (row & 7);
            gload16(Bb + (size_t)(n0 + row) * rs + kb + csrc * 16,
                    (char*)Bs[buf] + chunk * 16);
        }
    };

    int nsteps = K >> 6;                         // 71
    stage(0, 0);
    if (nsteps > 1) stage(1, 1);
    for (int s = 0; s < nsteps; ++s) {
        int cur = s & 1;
        if (s + 1 < nsteps) { asm volatile("s_waitcnt vmcnt(12)" ::: "memory"); }
        else                { asm volatile("s_waitcnt vmcnt(0)" ::: "memory"); }
        __builtin_amdgcn_s_barrier();            // stage(s) fully landed (all waves)
        bf16x8 af[4][2], bfr[4][2];
#pragma unroll
        for (int mi = 0; mi < 4; mi++) {
            int row = mi * 16 + lr;
#pragma unroll
            for (int kk = 0; kk < 2; kk++)
                af[mi][kk] = as_bf(*(const u16x8*)&As[cur][row * 64 + (((kk * 4 + lg) ^ (row & 7)) << 3)]);
        }
#pragma unroll
        for (int ni = 0; ni < 4; ni++) {
            int row = wn * 64 + ni * 16 + lr;
#pragma unroll
            for (int kk = 0; kk < 2; kk++)
                bfr[ni][kk] = as_bf(*(const u16x8*)&Bs[cur][row * 64 + (((kk * 4 + lg) ^ (row & 7)) << 3)]);
        }
        asm volatile("s_waitcnt lgkmcnt(0)" ::: "memory");   // frags in regs
        __builtin_amdgcn_s_barrier();            // all waves done reading buf cur
        if (s + 2 < nsteps) stage(s + 2, cur);   // loads fly under the MFMAs
#pragma unroll
        for (int kk = 0; kk < 2; kk++)
#pragma unroll
            for (int mi = 0; mi < 4; mi++)
#pragma unroll
                for (int ni = 0; ni < 4; ni++)
                    acc[mi][ni] = __builtin_amdgcn_mfma_f32_16x16x32_bf16(
                        af[mi][kk], bfr[ni][kk], acc[mi][ni], 0, 0, 0);
    }

    if (EPI == 0) {
        float* C = (float*)Cout;
#pragma unroll
        for (int mi = 0; mi < 4; mi++)
#pragma unroll
            for (int ni = 0; ni < 4; ni++) {
                int col = n0 + wn * 64 + ni * 16 + lr;
                if (col < n_store) {
#pragma unroll
                    for (int i = 0; i < 4; i++) {
                        int row = m0 + mi * 16 + 4 * lg + i;
                        C[(size_t)row * ldc + col] = acc[mi][ni][i];
                    }
                }
            }
    } else {
        int hh = nb * 2 + wn;                 // head index (0..73)
        if (hh == 72) {                       // v: write transposed [d][1024]
#pragma unroll
            for (int mi = 0; mi < 4; mi++)
#pragma unroll
                for (int ni = 0; ni < 4; ni++) {
                    int d = ni * 16 + lr;
                    int s0 = m0 + mi * 16 + 4 * lg;
                    u16x4 pk;
#pragma unroll
                    for (int i = 0; i < 4; i++) pk[i] = f2bf(acc[mi][ni][i]);
                    *(u16x4*)&v_out[(size_t)d * S_LEN + s0] = pk;
                }
        } else if (hh < 72) {                 // q (hh<71) / k (hh==71): rope
            unsigned short* qb = (unsigned short*)Cout;
            float qscale = (hh < 71) ? 0.125f : 1.0f;
#pragma unroll
            for (int mi = 0; mi < 4; mi++)
#pragma unroll
                for (int i = 0; i < 4; i++) {
                    int s = m0 + mi * 16 + 4 * lg + i;
                    float c0 = cs_t[s * 32 + lr],      g0 = sn_t[s * 32 + lr];
                    float c1 = cs_t[s * 32 + 16 + lr], g1 = sn_t[s * 32 + 16 + lr];
#pragma unroll
                    for (int ni = 0; ni < 4; ni++) {
                        float x  = acc[mi][ni][i];
                        float xp = acc[mi][ni ^ 2][i];
                        float c = (ni & 1) ? c1 : c0;
                        float g = (ni & 1) ? g1 : g0;
                        float r = (ni < 2) ? (x * c - xp * g) : (x * c + xp * g);
                        r *= qscale;
                        int d = ni * 16 + lr;
                        if (hh < 71) qb[(size_t)s * HID + hh * 64 + d] = f2bf(r);
                        else         k_out[(size_t)s * 64 + d] = f2bf(r);
                    }
                }
        }                                     // hh == 73: padding, skip
    }
}

// ---------- flash attention (MQA), split-K, LDS-shared K/V, counted-vmcnt ----------
// grid (40, 71), block 256. Block = (head, chunk c, 4 q-tiles j0..j0+3).
__global__ __launch_bounds__(256, 3) void attn_kernel(
        const unsigned short* __restrict__ qb, const unsigned short* __restrict__ kr,
        const unsigned short* __restrict__ vt, unsigned short* __restrict__ ctx,
        unsigned short* __restrict__ Opart, float2* __restrict__ MLpart) {
    __shared__ unsigned short Ks[2][64 * 64];
    __shared__ unsigned short Vs[2][64 * 64];
    __shared__ unsigned short Pl[4][16 * 72];
    int h = blockIdx.y;
    int u = blockIdx.x;
    int c, j0;
    if (u < 16)      { c = 0; j0 = u * 4; }
    else if (u < 28) { c = 1; j0 = 16 + (u - 16) * 4; }
    else if (u < 36) { c = 2; j0 = 32 + (u - 28) * 4; }
    else             { c = 3; j0 = 48 + (u - 36) * 4; }
    int t = threadIdx.x, wv = t >> 6, lane = t & 63, lr = lane & 15, lg = lane >> 4;
    int j = j0 + wv;
    int qs = j * 16 + lr;
    int k_lo = c * 256;
    int kend_w   = min((j + 1) * 16, k_lo + 256);
    int kend_max = min((j0 + 4) * 16, k_lo + 256);
    int nt = (kend_max - k_lo) >> 6;
    int nch = (j >> 4) + 1;
    int srow = t >> 3, sc16 = t & 7, sw = lr & 7;

    auto stage = [&](int ti, int buf) {          // 4 global_load_lds per thread
        size_t kbase = (size_t)(k_lo + ti * 64);
#pragma unroll
        for (int i = 0; i < 2; i++) {
            int row = i * 32 + srow;
            int csrc = sc16 ^ (row & 7);
            gload16((const char*)kr + (kbase + row) * 128 + csrc * 16,
                    (char*)Ks[buf] + (i * 256 + t) * 16);
        }
#pragma unroll
        for (int i = 0; i < 2; i++) {
            int row = i * 32 + srow;
            int csrc = sc16 ^ (row & 7);
            gload16((const char*)vt + (size_t)row * 2048 + kbase * 2 + csrc * 16,
                    (char*)Vs[buf] + (i * 256 + t) * 16);
        }
    };

    bf16x8 qf[2];
#pragma unroll
    for (int dc = 0; dc < 2; dc++)
        qf[dc] = as_bf(*(const u16x8*)&qb[(size_t)qs * HID + h * 64 + dc * 32 + 8 * lg]);

    float m_i = -1e30f, l_i = 0.0f;
    f32x4 o[4];
#pragma unroll
    for (int d4 = 0; d4 < 4; d4++) o[d4] = (f32x4)0.0f;

    stage(0, 0);
    if (nt > 1) stage(1, 1);

    for (int ti = 0; ti < nt; ti++) {
        int cur = ti & 1;
        if (ti + 1 < nt) { asm volatile("s_waitcnt vmcnt(4)" ::: "memory"); }
        else             { asm volatile("s_waitcnt vmcnt(0)" ::: "memory"); }
        __builtin_amdgcn_s_barrier();            // tile ti fully landed
        int k0 = k_lo + ti * 64;
        if (k0 < kend_w) {
            f32x4 st[4];
#pragma unroll
            for (int nc = 0; nc < 4; nc++) st[nc] = (f32x4)0.0f;
#pragma unroll
            for (int nc = 0; nc < 4; nc++) {
                int krow = nc * 16 + lr;
#pragma unroll
                for (int dc = 0; dc < 2; dc++) {
                    bf16x8 kf = as_bf(*(const u16x8*)&Ks[cur][krow * 64 + (((dc * 4 + lg) ^ sw) << 3)]);
                    st[nc] = __builtin_amdgcn_mfma_f32_16x16x32_bf16(kf, qf[dc], st[nc], 0, 0, 0);
                }
            }
            bool needmask = (k0 + 64 > j * 16);
            float mx = -1e30f;
            if (needmask) {
#pragma unroll
                for (int nc = 0; nc < 4; nc++)
#pragma unroll
                    for (int i = 0; i < 4; i++) {
                        int ks = k0 + nc * 16 + 4 * lg + i;
                        float v = (ks <= qs) ? st[nc][i] : -1e30f;
                        st[nc][i] = v;
                        mx = fmaxf(mx, v);
                    }
            } else {
#pragma unroll
                for (int nc = 0; nc < 4; nc++)
#pragma unroll
                    for (int i = 0; i < 4; i++) mx = fmaxf(mx, st[nc][i]);
            }
            mx = fmaxf(mx, __shfl_xor(mx, 16));
            mx = fmaxf(mx, __shfl_xor(mx, 32));
            // T13 defer-max: skip rescale while max grows by <= 8
            if (!__all(mx <= m_i + 8.0f)) {
                float mn = fmaxf(m_i, mx);
                float so = __expf(m_i - mn);
                l_i *= so;
#pragma unroll
                for (int d4 = 0; d4 < 4; d4++)
#pragma unroll
                    for (int i = 0; i < 4; i++) o[d4][i] *= so;
                m_i = mn;
            }
            float ps = 0.0f;
#pragma unroll
            for (int nc = 0; nc < 4; nc++)
#pragma unroll
                for (int i = 0; i < 4; i++) {
                    float v = st[nc][i];
                    float e = (!needmask || v > -1e29f) ? __expf(v - m_i) : 0.0f;
                    st[nc][i] = e;
                    ps += e;
                }
            ps += __shfl_xor(ps, 16);
            ps += __shfl_xor(ps, 32);
            l_i += ps;
            // P^T (lane-local) -> Pl[q=lr][k] (pad 72: conflict-free)
#pragma unroll
            for (int nc = 0; nc < 4; nc++) {
                *(unsigned*)&Pl[wv][lr * 72 + nc * 16 + 4 * lg]     = pk2(st[nc][0], st[nc][1]);
                *(unsigned*)&Pl[wv][lr * 72 + nc * 16 + 4 * lg + 2] = pk2(st[nc][2], st[nc][3]);
            }
            bf16x8 pb[2];
#pragma unroll
            for (int kk = 0; kk < 2; kk++)
                pb[kk] = as_bf(*(const u16x8*)&Pl[wv][lr * 72 + kk * 32 + 8 * lg]);
#pragma unroll
            for (int d4 = 0; d4 < 4; d4++) {
                int vrow = d4 * 16 + lr;
#pragma unroll
                for (int kk = 0; kk < 2; kk++) {
                    bf16x8 vf = as_bf(*(const u16x8*)&Vs[cur][vrow * 64 + (((kk * 4 + lg) ^ sw) << 3)]);
                    o[d4] = __builtin_amdgcn_mfma_f32_16x16x32_bf16(vf, pb[kk], o[d4], 0, 0, 0);
                }
            }
        }
        __builtin_amdgcn_s_barrier();            // all waves consumed buf cur
        if (ti + 2 < nt) stage(ti + 2, cur);     // overwrite buf cur
    }

    if (nch == 1) {
        float linv = 1.0f / l_i;
#pragma unroll
        for (int d4 = 0; d4 < 4; d4++) {
            u16x4 pk;
#pragma unroll
            for (int i = 0; i < 4; i++) pk[i] = f2bf(o[d4][i] * linv);
            *(u16x4*)&ctx[(size_t)qs * HID + h * 64 + d4 * 16 + 4 * lg] = pk;
        }
    } else {
        int pi = (h * 48 + (j - 16)) * 4 + c;
#pragma unroll
        for (int d4 = 0; d4 < 4; d4++) {
            u16x4 pk;
#pragma unroll
            for (int i = 0; i < 4; i++) pk[i] = f2bf(o[d4][i]);
            *(u16x4*)&Opart[(size_t)pi * 1024 + lr * 64 + d4 * 16 + 4 * lg] = pk;
        }
        if (lg == 0) MLpart[pi * 16 + lr] = make_float2(m_i, l_i);
    }
}

// ---------- split-K merge: one wave per (h, j>=16) ----------
__global__ __launch_bounds__(256) void merge_kernel(
        const unsigned short* __restrict__ Opart, const float2* __restrict__ MLpart,
        unsigned short* __restrict__ ctx) {
    int mu = blockIdx.x * 4 + (threadIdx.x >> 6);
    int lane = threadIdx.x & 63;
    int h = mu / 48, jj = mu % 48, j = 16 + jj;
    int nch = (j >> 4) + 1;
    int base = (h * 48 + jj) * 4;
    for (int q = 0; q < 16; q++) {
        float m[4], l[4], w[4];
        float M = -1e30f;
        for (int c = 0; c < nch; c++) {
            float2 ml = MLpart[(base + c) * 16 + q];
            m[c] = ml.x; l[c] = ml.y;
            M = fmaxf(M, m[c]);
        }
        float L = 0.0f;
        for (int c = 0; c < nch; c++) { w[c] = __expf(m[c] - M); L += l[c] * w[c]; }
        float acc = 0.0f;
        for (int c = 0; c < nch; c++)
            acc += w[c] * bf2f(Opart[(size_t)(base + c) * 1024 + q * 64 + lane]);
        ctx[(size_t)(j * 16 + q) * HID + h * 64 + lane] = f2bf(acc / L);
    }
}

extern "C" void kernel_launch(void* const* d_in, const int* in_sizes, int n_in,
                              void* d_out, int out_size, void* d_ws, size_t ws_size,
                              hipStream_t stream) {
    const float* hs      = (const float*)d_in[0];
    // d_in[1] = attention_mask (analytic causal mask used instead)
    const float* qkv_w   = (const float*)d_in[2];
    const float* dense_w = (const float*)d_in[3];
    float* out = (float*)d_out;

    char* ws = (char*)d_ws;
    size_t off = 0;
    auto alloc = [&](size_t bytes) -> void* {
        void* p = ws + off;
        off += (bytes + 255) & ~(size_t)255;
        return p;
    };
    unsigned short* x_bf   = (unsigned short*)alloc((size_t)S_LEN * HID * 2);      // 9.3 MB
    unsigned short* wqkvT  = (unsigned short*)alloc((size_t)NQKV_PAD * HID * 2);   // 43.0 MB
    unsigned short* q_bf   = (unsigned short*)alloc((size_t)S_LEN * HID * 2);      // 9.3 MB
    unsigned short* k_rope = (unsigned short*)alloc((size_t)S_LEN * 64 * 2);
    unsigned short* v_t    = (unsigned short*)alloc((size_t)64 * S_LEN * 2);
    unsigned short* ctx    = (unsigned short*)alloc((size_t)S_LEN * HID * 2);      // 9.3 MB
    unsigned short* wdT    = (unsigned short*)alloc((size_t)ND_PAD * HID * 2);     // 41.9 MB
    float*          cs_t   = (float*)alloc((size_t)S_LEN * 32 * 4);
    float*          sn_t   = (float*)alloc((size_t)S_LEN * 32 * 4);
    (void)ws_size;   // ~113 MB
    // Opart/MLpart alias wqkvT (dead after QKV GEMM; attn/merge run later)
    unsigned short* Opart  = wqkvT;                                   // 27.9 MB
    float2*         MLpart = (float2*)((char*)wqkvT + (size_t)71 * 48 * 4 * 1024 * 2);

    cvt_x_kernel<<<dim3(S_LEN * HID / 1024), dim3(256), 0, stream>>>(
        (const float4*)hs, (ushort4*)x_bf);
    cvt_wT_kernel<<<dim3(NQKV_PAD / 64, HID / 64), dim3(256), 0, stream>>>(
        qkv_w, wqkvT, HID, NQKV);
    cvt_wT_kernel<<<dim3(ND_PAD / 64, HID / 64), dim3(256), 0, stream>>>(
        dense_w, wdT, HID, HID);
    rope_table_kernel<<<dim3(S_LEN), dim3(32), 0, stream>>>(cs_t, sn_t);

    // QKV GEMM + fused extract/RoPE epilogue (592 = 8 XCD-chunks of 74)
    gemm_bt_kernel<1><<<dim3(16 * NQKV_PAD / 128), dim3(128), 0, stream>>>(
        x_bf, wqkvT, q_bf, cs_t, sn_t, k_rope, v_t, HID, HID, NQKV);

    attn_kernel<<<dim3(40, NH), dim3(256), 0, stream>>>(
        q_bf, k_rope, v_t, ctx, Opart, MLpart);

    merge_kernel<<<dim3(NH * 48 / 4), dim3(256), 0, stream>>>(Opart, MLpart, ctx);

    // dense GEMM (576 = 8 XCD-chunks of 72)
    gemm_bt_kernel<0><<<dim3(16 * ND_PAD / 128), dim3(128), 0, stream>>>(
        ctx, wdT, out, nullptr, nullptr, nullptr, nullptr, HID, HID, HID);
}

// Round 14
// 251.875 us; speedup vs baseline: 1.3071x; 1.0290x over previous
//
#include <hip/hip_runtime.h>

#define S_LEN 1024
#define HID   4544            // 71*64; K of both GEMMs
#define NH    71
#define NQKV  4672            // 73*64
#define NQKV_PAD 4736         // 37*128
#define ND_PAD   4608         // 36*128

#define XB (S_LEN * HID / 1024)                 // 4544 cvt_x blocks
#define WB ((NQKV_PAD / 64) * (HID / 64))       // 5254 qkv cvt_wT blocks
#define RB 128                                  // rope-table blocks

typedef __attribute__((ext_vector_type(4)))  float f32x4;
typedef __attribute__((ext_vector_type(4))) unsigned short u16x4;
typedef __attribute__((ext_vector_type(8))) unsigned short u16x8;
typedef __attribute__((ext_vector_type(8))) __bf16 bf16x8;

__device__ __forceinline__ bf16x8 as_bf(u16x8 v) { return __builtin_bit_cast(bf16x8, v); }

__device__ __forceinline__ unsigned short f2bf(float f) {
    unsigned u = __builtin_bit_cast(unsigned, f);
    return (unsigned short)((u + 0x7FFFu + ((u >> 16) & 1u)) >> 16);  // RNE
}
__device__ __forceinline__ float bf2f(unsigned short u) {
    return __builtin_bit_cast(float, (unsigned)u << 16);
}
__device__ __forceinline__ unsigned pk2(float a, float b) {   // packed bf16x2, RNE
    return (unsigned)f2bf(a) | ((unsigned)f2bf(b) << 16);
}
__device__ __forceinline__ void gload16(const void* g, void* l) {
    __builtin_amdgcn_global_load_lds((const __attribute__((address_space(1))) unsigned int*)g,
                                     (__attribute__((address_space(3))) unsigned int*)l,
                                     16, 0, 0);
}

// ---------- fused prep: cvt_x | qkv cvt_wT | rope table, one launch ----------
__global__ __launch_bounds__(256) void prep_kernel(
        const float4* __restrict__ x, ushort4* __restrict__ y,
        const float* __restrict__ qkv_w, unsigned short* __restrict__ wqkvT,
        float* __restrict__ cs, float* __restrict__ sn) {
    __shared__ float tb[64][65];
    int bx = blockIdx.x, t = threadIdx.x;
    if (bx < XB) {                                 // x: fp32 -> bf16
        int i = bx * 256 + t;
        float4 v = x[i];
        ushort4 r;
        r.x = f2bf(v.x); r.y = f2bf(v.y); r.z = f2bf(v.z); r.w = f2bf(v.w);
        y[i] = r;
    } else if (bx < XB + WB) {                     // qkv_w: [K][N] fp32 -> [Npad][K] bf16
        int idx = bx - XB;
        int n0 = (idx % (NQKV_PAD / 64)) * 64, k0 = (idx / (NQKV_PAD / 64)) * 64;
        int tx = t & 15, ty = t >> 4;              // 16 x 16
#pragma unroll
        for (int r = 0; r < 64; r += 16) {
            int k = k0 + ty + r, n = n0 + tx * 4;
            float4 v = make_float4(0.f, 0.f, 0.f, 0.f);
            if (n < NQKV) v = *(const float4*)&qkv_w[(size_t)k * NQKV + n];
            tb[ty + r][tx * 4 + 0] = v.x;
            tb[ty + r][tx * 4 + 1] = v.y;
            tb[ty + r][tx * 4 + 2] = v.z;
            tb[ty + r][tx * 4 + 3] = v.w;
        }
        __syncthreads();
        int nr = t >> 2, kq = (t & 3) * 16;
        unsigned short tmp[16];
#pragma unroll
        for (int z = 0; z < 16; z++) tmp[z] = f2bf(tb[kq + z][nr]);
        u16x8* dst = (u16x8*)&wqkvT[(size_t)(n0 + nr) * HID + k0 + kq];
        dst[0] = *(const u16x8*)&tmp[0];
        dst[1] = *(const u16x8*)&tmp[8];
    } else {                                       // rope cos/sin table
        int gi = (bx - XB - WB) * 256 + t;         // 0..32767
        int s = gi >> 5, i = gi & 31;
        float inv = powf(10000.0f, -(2.0f * (float)i) / 64.0f);
        float f = (float)s * inv;
        cs[s * 32 + i] = cosf(f);
        sn[s * 32 + i] = sinf(f);
    }
}

// ---------- bf16 MFMA GEMM: BM=64 BN=128 BK=64, 2 waves, wave = 64x64 ----------
// r13 structure (best measured: 75 us, 0 conflicts). Blocks >= gemm_blocks run
// a 128-thread dense-weight cvt_wT instead (fused tail: rides the GEMM's idle
// HBM BW + free block slots; dispatched after all GEMM blocks).
// EPI 0: C fp32 (guard col < n_store). EPI 1: QKV epilogue, head = 2*nb+wn.
template<int EPI>
__global__ __launch_bounds__(128, 2) void gemm_bt_kernel(
        const unsigned short* __restrict__ A, const unsigned short* __restrict__ BT,
        void* __restrict__ Cout, const float* __restrict__ cs_t,
        const float* __restrict__ sn_t, unsigned short* __restrict__ k_out,
        unsigned short* __restrict__ v_out, int K, int ldc, int n_store,
        const float* __restrict__ w2, unsigned short* __restrict__ wt2,
        int gemm_blocks) {
    __shared__ char smem[49152];
    unsigned short* As0 = (unsigned short*)smem;            // 2 x 64x64  (8KB each)
    unsigned short* Bs0 = (unsigned short*)(smem + 16384);  // 2 x 128x64 (16KB each)
    int t = threadIdx.x;                                    // 0..127

    if ((int)blockIdx.x >= gemm_blocks) {
        // ---- fused dense cvt_wT: [K][HID] fp32 -> [ND_PAD][K] bf16, 64x64 tile ----
        float (*tb)[65] = (float(*)[65])smem;
        int idx = (int)blockIdx.x - gemm_blocks;
        int n0 = (idx % (ND_PAD / 64)) * 64, k0 = (idx / (ND_PAD / 64)) * 64;
        int tx = t & 15, ty = t >> 4;              // 16 x 8
#pragma unroll
        for (int r = 0; r < 64; r += 8) {
            int k = k0 + ty + r, n = n0 + tx * 4;
            float4 v = make_float4(0.f, 0.f, 0.f, 0.f);
            if (n < HID) v = *(const float4*)&w2[(size_t)k * HID + n];
            tb[ty + r][tx * 4 + 0] = v.x;
            tb[ty + r][tx * 4 + 1] = v.y;
            tb[ty + r][tx * 4 + 2] = v.z;
            tb[ty + r][tx * 4 + 3] = v.w;
        }
        __syncthreads();
        int nr = t >> 1, kh = (t & 1) * 32;        // row n, k-half
        unsigned short tmp[32];
#pragma unroll
        for (int z = 0; z < 32; z++) tmp[z] = f2bf(tb[kh + z][nr]);
        u16x8* dst = (u16x8*)&wt2[(size_t)(n0 + nr) * HID + k0 + kh];
        dst[0] = *(const u16x8*)&tmp[0];
        dst[1] = *(const u16x8*)&tmp[8];
        dst[2] = *(const u16x8*)&tmp[16];
        dst[3] = *(const u16x8*)&tmp[24];
        return;
    }

    int p = blockIdx.x;
    int per = gemm_blocks >> 3;                  // blocks per XCD chunk
    int l = (p & 7) * per + (p >> 3);
    int msl = l & 15, nb = l >> 4;
    int m0 = msl * 64, n0 = nb * 128;
    int wn = t >> 6;                             // wave = n-half
    int lane = t & 63, lr = lane & 15, lg = lane >> 4;

    f32x4 acc[4][4];
#pragma unroll
    for (int mi = 0; mi < 4; mi++)
#pragma unroll
        for (int ni = 0; ni < 4; ni++) acc[mi][ni] = (f32x4)0.0f;

    const char* Ab = (const char*)A;
    const char* Bb = (const char*)BT;
    size_t rs = (size_t)K * 2;

    auto stage = [&](int step, int buf) {        // 12 gload16 per thread
        size_t kb = (size_t)step * 128;          // 64 elems * 2B
#pragma unroll
        for (int i = 0; i < 4; i++) {            // A: 512 chunks of 16B
            int chunk = i * 128 + t;
            int row = chunk >> 3, c8 = chunk & 7;
            int csrc = c8 ^ (row & 7);
            gload16(Ab + (size_t)(m0 + row) * rs + kb + csrc * 16,
                    (char*)As0 + buf * 8192 + chunk * 16);
        }
#pragma unroll
        for (int i = 0; i < 8; i++) {            // B: 1024 chunks
            int chunk = i * 128 + t;
            int row = chunk >> 3, c8 = chunk & 7;
            int csrc = c8 ^ (row & 7);
            gload16(Bb + (size_t)(n0 + row) * rs + kb + csrc * 16,
                    (char*)Bs0 + buf * 16384 + chunk * 16);
        }
    };

    int nsteps = K >> 6;                         // 71
    stage(0, 0);
    if (nsteps > 1) stage(1, 1);
    for (int s = 0; s < nsteps; ++s) {
        int cur = s & 1;
        if (s + 1 < nsteps) { asm volatile("s_waitcnt vmcnt(12)" ::: "memory"); }
        else                { asm volatile("s_waitcnt vmcnt(0)" ::: "memory"); }
        __builtin_amdgcn_s_barrier();            // stage(s) fully landed (all waves)
        bf16x8 af[4][2], bfr[4][2];
#pragma unroll
        for (int mi = 0; mi < 4; mi++) {
            int row = mi * 16 + lr;
#pragma unroll
            for (int kk = 0; kk < 2; kk++)
                af[mi][kk] = as_bf(*(const u16x8*)&As0[cur * 4096 + row * 64 + (((kk * 4 + lg) ^ (row & 7)) << 3)]);
        }
#pragma unroll
        for (int ni = 0; ni < 4; ni++) {
            int row = wn * 64 + ni * 16 + lr;
#pragma unroll
            for (int kk = 0; kk < 2; kk++)
                bfr[ni][kk] = as_bf(*(const u16x8*)&Bs0[cur * 8192 + row * 64 + (((kk * 4 + lg) ^ (row & 7)) << 3)]);
        }
        asm volatile("s_waitcnt lgkmcnt(0)" ::: "memory");   // frags in regs
        __builtin_amdgcn_s_barrier();            // all waves done reading buf cur
        if (s + 2 < nsteps) stage(s + 2, cur);   // loads fly under the MFMAs
#pragma unroll
        for (int kk = 0; kk < 2; kk++)
#pragma unroll
            for (int mi = 0; mi < 4; mi++)
#pragma unroll
                for (int ni = 0; ni < 4; ni++)
                    acc[mi][ni] = __builtin_amdgcn_mfma_f32_16x16x32_bf16(
                        af[mi][kk], bfr[ni][kk], acc[mi][ni], 0, 0, 0);
    }

    if (EPI == 0) {
        float* C = (float*)Cout;
#pragma unroll
        for (int mi = 0; mi < 4; mi++)
#pragma unroll
            for (int ni = 0; ni < 4; ni++) {
                int col = n0 + wn * 64 + ni * 16 + lr;
                if (col < n_store) {
#pragma unroll
                    for (int i = 0; i < 4; i++) {
                        int row = m0 + mi * 16 + 4 * lg + i;
                        C[(size_t)row * ldc + col] = acc[mi][ni][i];
                    }
                }
            }
    } else {
        int hh = nb * 2 + wn;                 // head index (0..73)
        if (hh == 72) {                       // v: write transposed [d][1024]
#pragma unroll
            for (int mi = 0; mi < 4; mi++)
#pragma unroll
                for (int ni = 0; ni < 4; ni++) {
                    int d = ni * 16 + lr;
                    int s0 = m0 + mi * 16 + 4 * lg;
                    u16x4 pk;
#pragma unroll
                    for (int i = 0; i < 4; i++) pk[i] = f2bf(acc[mi][ni][i]);
                    *(u16x4*)&v_out[(size_t)d * S_LEN + s0] = pk;
                }
        } else if (hh < 72) {                 // q (hh<71) / k (hh==71): rope
            unsigned short* qb = (unsigned short*)Cout;
            float qscale = (hh < 71) ? 0.125f : 1.0f;
#pragma unroll
            for (int mi = 0; mi < 4; mi++)
#pragma unroll
                for (int i = 0; i < 4; i++) {
                    int s = m0 + mi * 16 + 4 * lg + i;
                    float c0 = cs_t[s * 32 + lr],      g0 = sn_t[s * 32 + lr];
                    float c1 = cs_t[s * 32 + 16 + lr], g1 = sn_t[s * 32 + 16 + lr];
#pragma unroll
                    for (int ni = 0; ni < 4; ni++) {
                        float x  = acc[mi][ni][i];
                        float xp = acc[mi][ni ^ 2][i];
                        float c = (ni & 1) ? c1 : c0;
                        float g = (ni & 1) ? g1 : g0;
                        float r = (ni < 2) ? (x * c - xp * g) : (x * c + xp * g);
                        r *= qscale;
                        int d = ni * 16 + lr;
                        if (hh < 71) qb[(size_t)s * HID + hh * 64 + d] = f2bf(r);
                        else         k_out[(size_t)s * 64 + d] = f2bf(r);
                    }
                }
        }                                     // hh == 73: padding, skip
    }
}

// ---------- flash attention (MQA), split-K, LDS-shared K/V, counted-vmcnt ----------
// grid (40, 71), block 256. Block = (head, chunk c, 4 q-tiles j0..j0+3).
__global__ __launch_bounds__(256, 3) void attn_kernel(
        const unsigned short* __restrict__ qb, const unsigned short* __restrict__ kr,
        const unsigned short* __restrict__ vt, unsigned short* __restrict__ ctx,
        unsigned short* __restrict__ Opart, float2* __restrict__ MLpart) {
    __shared__ unsigned short Ks[2][64 * 64];
    __shared__ unsigned short Vs[2][64 * 64];
    __shared__ unsigned short Pl[4][16 * 72];
    int h = blockIdx.y;
    int u = blockIdx.x;
    int c, j0;
    if (u < 16)      { c = 0; j0 = u * 4; }
    else if (u < 28) { c = 1; j0 = 16 + (u - 16) * 4; }
    else if (u < 36) { c = 2; j0 = 32 + (u - 28) * 4; }
    else             { c = 3; j0 = 48 + (u - 36) * 4; }
    int t = threadIdx.x, wv = t >> 6, lane = t & 63, lr = lane & 15, lg = lane >> 4;
    int j = j0 + wv;
    int qs = j * 16 + lr;
    int k_lo = c * 256;
    int kend_w   = min((j + 1) * 16, k_lo + 256);
    int kend_max = min((j0 + 4) * 16, k_lo + 256);
    int nt = (kend_max - k_lo) >> 6;
    int nch = (j >> 4) + 1;
    int srow = t >> 3, sc16 = t & 7, sw = lr & 7;

    auto stage = [&](int ti, int buf) {          // 4 global_load_lds per thread
        size_t kbase = (size_t)(k_lo + ti * 64);
#pragma unroll
        for (int i = 0; i < 2; i++) {
            int row = i * 32 + srow;
            int csrc = sc16 ^ (row & 7);
            gload16((const char*)kr + (kbase + row) * 128 + csrc * 16,
                    (char*)Ks[buf] + (i * 256 + t) * 16);
        }
#pragma unroll
        for (int i = 0; i < 2; i++) {
            int row = i * 32 + srow;
            int csrc = sc16 ^ (row & 7);
            gload16((const char*)vt + (size_t)row * 2048 + kbase * 2 + csrc * 16,
                    (char*)Vs[buf] + (i * 256 + t) * 16);
        }
    };

    bf16x8 qf[2];
#pragma unroll
    for (int dc = 0; dc < 2; dc++)
        qf[dc] = as_bf(*(const u16x8*)&qb[(size_t)qs * HID + h * 64 + dc * 32 + 8 * lg]);

    float m_i = -1e30f, l_i = 0.0f;
    f32x4 o[4];
#pragma unroll
    for (int d4 = 0; d4 < 4; d4++) o[d4] = (f32x4)0.0f;

    stage(0, 0);
    if (nt > 1) stage(1, 1);

    for (int ti = 0; ti < nt; ti++) {
        int cur = ti & 1;
        if (ti + 1 < nt) { asm volatile("s_waitcnt vmcnt(4)" ::: "memory"); }
        else             { asm volatile("s_waitcnt vmcnt(0)" ::: "memory"); }
        __builtin_amdgcn_s_barrier();            // tile ti fully landed
        int k0 = k_lo + ti * 64;
        if (k0 < kend_w) {
            f32x4 st[4];
#pragma unroll
            for (int nc = 0; nc < 4; nc++) st[nc] = (f32x4)0.0f;
#pragma unroll
            for (int nc = 0; nc < 4; nc++) {
                int krow = nc * 16 + lr;
#pragma unroll
                for (int dc = 0; dc < 2; dc++) {
                    bf16x8 kf = as_bf(*(const u16x8*)&Ks[cur][krow * 64 + (((dc * 4 + lg) ^ sw) << 3)]);
                    st[nc] = __builtin_amdgcn_mfma_f32_16x16x32_bf16(kf, qf[dc], st[nc], 0, 0, 0);
                }
            }
            bool needmask = (k0 + 64 > j * 16);
            float mx = -1e30f;
            if (needmask) {
#pragma unroll
                for (int nc = 0; nc < 4; nc++)
#pragma unroll
                    for (int i = 0; i < 4; i++) {
                        int ks = k0 + nc * 16 + 4 * lg + i;
                        float v = (ks <= qs) ? st[nc][i] : -1e30f;
                        st[nc][i] = v;
                        mx = fmaxf(mx, v);
                    }
            } else {
#pragma unroll
                for (int nc = 0; nc < 4; nc++)
#pragma unroll
                    for (int i = 0; i < 4; i++) mx = fmaxf(mx, st[nc][i]);
            }
            mx = fmaxf(mx, __shfl_xor(mx, 16));
            mx = fmaxf(mx, __shfl_xor(mx, 32));
            // T13 defer-max: skip rescale while max grows by <= 8
            if (!__all(mx <= m_i + 8.0f)) {
                float mn = fmaxf(m_i, mx);
                float so = __expf(m_i - mn);
                l_i *= so;
#pragma unroll
                for (int d4 = 0; d4 < 4; d4++)
#pragma unroll
                    for (int i = 0; i < 4; i++) o[d4][i] *= so;
                m_i = mn;
            }
            float ps = 0.0f;
#pragma unroll
            for (int nc = 0; nc < 4; nc++)
#pragma unroll
                for (int i = 0; i < 4; i++) {
                    float v = st[nc][i];
                    float e = (!needmask || v > -1e29f) ? __expf(v - m_i) : 0.0f;
                    st[nc][i] = e;
                    ps += e;
                }
            ps += __shfl_xor(ps, 16);
            ps += __shfl_xor(ps, 32);
            l_i += ps;
            // P^T (lane-local) -> Pl[q=lr][k] (pad 72: conflict-free)
#pragma unroll
            for (int nc = 0; nc < 4; nc++) {
                *(unsigned*)&Pl[wv][lr * 72 + nc * 16 + 4 * lg]     = pk2(st[nc][0], st[nc][1]);
                *(unsigned*)&Pl[wv][lr * 72 + nc * 16 + 4 * lg + 2] = pk2(st[nc][2], st[nc][3]);
            }
            bf16x8 pb[2];
#pragma unroll
            for (int kk = 0; kk < 2; kk++)
                pb[kk] = as_bf(*(const u16x8*)&Pl[wv][lr * 72 + kk * 32 + 8 * lg]);
#pragma unroll
            for (int d4 = 0; d4 < 4; d4++) {
                int vrow = d4 * 16 + lr;
#pragma unroll
                for (int kk = 0; kk < 2; kk++) {
                    bf16x8 vf = as_bf(*(const u16x8*)&Vs[cur][vrow * 64 + (((kk * 4 + lg) ^ sw) << 3)]);
                    o[d4] = __builtin_amdgcn_mfma_f32_16x16x32_bf16(vf, pb[kk], o[d4], 0, 0, 0);
                }
            }
        }
        __builtin_amdgcn_s_barrier();            // all waves consumed buf cur
        if (ti + 2 < nt) stage(ti + 2, cur);     // overwrite buf cur
    }

    if (nch == 1) {
        float linv = 1.0f / l_i;
#pragma unroll
        for (int d4 = 0; d4 < 4; d4++) {
            u16x4 pk;
#pragma unroll
            for (int i = 0; i < 4; i++) pk[i] = f2bf(o[d4][i] * linv);
            *(u16x4*)&ctx[(size_t)qs * HID + h * 64 + d4 * 16 + 4 * lg] = pk;
        }
    } else {
        int pi = (h * 48 + (j - 16)) * 4 + c;
#pragma unroll
        for (int d4 = 0; d4 < 4; d4++) {
            u16x4 pk;
#pragma unroll
            for (int i = 0; i < 4; i++) pk[i] = f2bf(o[d4][i]);
            *(u16x4*)&Opart[(size_t)pi * 1024 + lr * 64 + d4 * 16 + 4 * lg] = pk;
        }
        if (lg == 0) MLpart[pi * 16 + lr] = make_float2(m_i, l_i);
    }
}

// ---------- split-K merge: one wave per (h, j>=16) ----------
__global__ __launch_bounds__(256) void merge_kernel(
        const unsigned short* __restrict__ Opart, const float2* __restrict__ MLpart,
        unsigned short* __restrict__ ctx) {
    int mu = blockIdx.x * 4 + (threadIdx.x >> 6);
    int lane = threadIdx.x & 63;
    int h = mu / 48, jj = mu % 48, j = 16 + jj;
    int nch = (j >> 4) + 1;
    int base = (h * 48 + jj) * 4;
    for (int q = 0; q < 16; q++) {
        float m[4], l[4], w[4];
        float M = -1e30f;
        for (int c = 0; c < nch; c++) {
            float2 ml = MLpart[(base + c) * 16 + q];
            m[c] = ml.x; l[c] = ml.y;
            M = fmaxf(M, m[c]);
        }
        float L = 0.0f;
        for (int c = 0; c < nch; c++) { w[c] = __expf(m[c] - M); L += l[c] * w[c]; }
        float acc = 0.0f;
        for (int c = 0; c < nch; c++)
            acc += w[c] * bf2f(Opart[(size_t)(base + c) * 1024 + q * 64 + lane]);
        ctx[(size_t)(j * 16 + q) * HID + h * 64 + lane] = f2bf(acc / L);
    }
}

extern "C" void kernel_launch(void* const* d_in, const int* in_sizes, int n_in,
                              void* d_out, int out_size, void* d_ws, size_t ws_size,
                              hipStream_t stream) {
    const float* hs      = (const float*)d_in[0];
    // d_in[1] = attention_mask (analytic causal mask used instead)
    const float* qkv_w   = (const float*)d_in[2];
    const float* dense_w = (const float*)d_in[3];
    float* out = (float*)d_out;

    char* ws = (char*)d_ws;
    size_t off = 0;
    auto alloc = [&](size_t bytes) -> void* {
        void* p = ws + off;
        off += (bytes + 255) & ~(size_t)255;
        return p;
    };
    unsigned short* x_bf   = (unsigned short*)alloc((size_t)S_LEN * HID * 2);      // 9.3 MB
    unsigned short* wqkvT  = (unsigned short*)alloc((size_t)NQKV_PAD * HID * 2);   // 43.0 MB
    unsigned short* q_bf   = (unsigned short*)alloc((size_t)S_LEN * HID * 2);      // 9.3 MB
    unsigned short* k_rope = (unsigned short*)alloc((size_t)S_LEN * 64 * 2);
    unsigned short* v_t    = (unsigned short*)alloc((size_t)64 * S_LEN * 2);
    unsigned short* ctx    = (unsigned short*)alloc((size_t)S_LEN * HID * 2);      // 9.3 MB
    unsigned short* wdT    = (unsigned short*)alloc((size_t)ND_PAD * HID * 2);     // 41.9 MB
    float*          cs_t   = (float*)alloc((size_t)S_LEN * 32 * 4);
    float*          sn_t   = (float*)alloc((size_t)S_LEN * 32 * 4);
    (void)ws_size;   // ~113 MB
    // Opart/MLpart alias wqkvT (dead after QKV GEMM; attn/merge run later).
    // wdT is written by the fused cvt tail of the QKV-GEMM launch and read by
    // the dense GEMM — stream-ordered, no overlap with Opart.
    unsigned short* Opart  = wqkvT;                                   // 27.9 MB
    float2*         MLpart = (float2*)((char*)wqkvT + (size_t)71 * 48 * 4 * 1024 * 2);

    // 1. fused prep: cvt_x | qkv cvt_wT | rope table
    prep_kernel<<<dim3(XB + WB + RB), dim3(256), 0, stream>>>(
        (const float4*)hs, (ushort4*)x_bf, qkv_w, wqkvT, cs_t, sn_t);

    // 2. QKV GEMM (592 gemm blocks, 8 XCD-chunks of 74) + fused dense cvt_wT
    //    tail (5112 blocks) riding the GEMM's spare HBM BW / block slots.
    gemm_bt_kernel<1><<<dim3(592 + (ND_PAD / 64) * (HID / 64)), dim3(128), 0, stream>>>(
        x_bf, wqkvT, q_bf, cs_t, sn_t, k_rope, v_t, HID, HID, NQKV,
        dense_w, wdT, 592);

    attn_kernel<<<dim3(40, NH), dim3(256), 0, stream>>>(
        q_bf, k_rope, v_t, ctx, Opart, MLpart);

    merge_kernel<<<dim3(NH * 48 / 4), dim3(256), 0, stream>>>(Opart, MLpart, ctx);

    // 3. dense GEMM (576 = 8 XCD-chunks of 72, no cvt tail)
    gemm_bt_kernel<0><<<dim3(576), dim3(128), 0, stream>>>(
        ctx, wdT, out, nullptr, nullptr, nullptr, nullptr, HID, HID, HID,
        nullptr, nullptr, 576);
}

// Round 15
// 251.727 us; speedup vs baseline: 1.3078x; 1.0006x over previous
//
#include <hip/hip_runtime.h>

#define S_LEN 1024
#define HID   4544            // 71*64; K of both GEMMs
#define NH    71
#define NQKV  4672            // 73*64
#define NQKV_PAD 4736         // 37*128
#define ND_PAD   4608         // 36*128

#define XB (S_LEN * HID / 1024)                 // 4544 cvt_x blocks
#define WB ((NQKV_PAD / 64) * (HID / 64))       // 5254 qkv cvt_wT blocks
#define RB 128                                  // rope-table blocks

typedef __attribute__((ext_vector_type(4)))  float f32x4;
typedef __attribute__((ext_vector_type(4))) unsigned short u16x4;
typedef __attribute__((ext_vector_type(8))) unsigned short u16x8;
typedef __attribute__((ext_vector_type(8))) __bf16 bf16x8;

__device__ __forceinline__ bf16x8 as_bf(u16x8 v) { return __builtin_bit_cast(bf16x8, v); }

__device__ __forceinline__ unsigned short f2bf(float f) {
    unsigned u = __builtin_bit_cast(unsigned, f);
    return (unsigned short)((u + 0x7FFFu + ((u >> 16) & 1u)) >> 16);  // RNE
}
__device__ __forceinline__ float bf2f(unsigned short u) {
    return __builtin_bit_cast(float, (unsigned)u << 16);
}
__device__ __forceinline__ unsigned pk2(float a, float b) {   // packed bf16x2, RNE
    return (unsigned)f2bf(a) | ((unsigned)f2bf(b) << 16);
}
__device__ __forceinline__ void gload16(const void* g, void* l) {
    __builtin_amdgcn_global_load_lds((const __attribute__((address_space(1))) unsigned int*)g,
                                     (__attribute__((address_space(3))) unsigned int*)l,
                                     16, 0, 0);
}

// ---------- fused prep: cvt_x | qkv cvt_wT | rope table, one launch ----------
__global__ __launch_bounds__(256) void prep_kernel(
        const float4* __restrict__ x, ushort4* __restrict__ y,
        const float* __restrict__ qkv_w, unsigned short* __restrict__ wqkvT,
        float* __restrict__ cs, float* __restrict__ sn) {
    __shared__ float tb[64][65];
    int bx = blockIdx.x, t = threadIdx.x;
    if (bx < XB) {                                 // x: fp32 -> bf16
        int i = bx * 256 + t;
        float4 v = x[i];
        ushort4 r;
        r.x = f2bf(v.x); r.y = f2bf(v.y); r.z = f2bf(v.z); r.w = f2bf(v.w);
        y[i] = r;
    } else if (bx < XB + WB) {                     // qkv_w: [K][N] fp32 -> [Npad][K] bf16
        int idx = bx - XB;
        int n0 = (idx % (NQKV_PAD / 64)) * 64, k0 = (idx / (NQKV_PAD / 64)) * 64;
        int tx = t & 15, ty = t >> 4;              // 16 x 16
#pragma unroll
        for (int r = 0; r < 64; r += 16) {
            int k = k0 + ty + r, n = n0 + tx * 4;
            float4 v = make_float4(0.f, 0.f, 0.f, 0.f);
            if (n < NQKV) v = *(const float4*)&qkv_w[(size_t)k * NQKV + n];
            tb[ty + r][tx * 4 + 0] = v.x;
            tb[ty + r][tx * 4 + 1] = v.y;
            tb[ty + r][tx * 4 + 2] = v.z;
            tb[ty + r][tx * 4 + 3] = v.w;
        }
        __syncthreads();
        int nr = t >> 2, kq = (t & 3) * 16;
        unsigned short tmp[16];
#pragma unroll
        for (int z = 0; z < 16; z++) tmp[z] = f2bf(tb[kq + z][nr]);
        u16x8* dst = (u16x8*)&wqkvT[(size_t)(n0 + nr) * HID + k0 + kq];
        dst[0] = *(const u16x8*)&tmp[0];
        dst[1] = *(const u16x8*)&tmp[8];
    } else {                                       // rope cos/sin table
        int gi = (bx - XB - WB) * 256 + t;         // 0..32767
        int s = gi >> 5, i = gi & 31;
        float inv = powf(10000.0f, -(2.0f * (float)i) / 64.0f);
        float f = (float)s * inv;
        cs[s * 32 + i] = cosf(f);
        sn[s * 32 + i] = sinf(f);
    }
}

// ---------- bf16 MFMA GEMM: BM=64 BN=128 BK=64, 2 waves, wave = 64x64 ----------
// Clean r13 structure (best measured: 75 us, 0 conflicts). Depth-2 counted
// vmcnt(12), chunked XCD map m-fastest, both-sides swizzle.
// EPI 0: C fp32 (guard col < n_store). EPI 1: QKV epilogue, head = 2*nb+wn.
template<int EPI>
__global__ __launch_bounds__(128, 2) void gemm_bt_kernel(
        const unsigned short* __restrict__ A, const unsigned short* __restrict__ BT,
        void* __restrict__ Cout, const float* __restrict__ cs_t,
        const float* __restrict__ sn_t, unsigned short* __restrict__ k_out,
        unsigned short* __restrict__ v_out, int K, int ldc, int n_store) {
    __shared__ unsigned short As[2][64 * 64];    // 8KB each
    __shared__ unsigned short Bs[2][128 * 64];   // 16KB each
    int p = blockIdx.x;
    int per = gridDim.x >> 3;                    // blocks per XCD chunk
    int l = (p & 7) * per + (p >> 3);
    int msl = l & 15, nb = l >> 4;
    int m0 = msl * 64, n0 = nb * 128;
    int t = threadIdx.x;                         // 0..127
    int wn = t >> 6;                             // wave = n-half
    int lane = t & 63, lr = lane & 15, lg = lane >> 4;

    f32x4 acc[4][4];
#pragma unroll
    for (int mi = 0; mi < 4; mi++)
#pragma unroll
        for (int ni = 0; ni < 4; ni++) acc[mi][ni] = (f32x4)0.0f;

    const char* Ab = (const char*)A;
    const char* Bb = (const char*)BT;
    size_t rs = (size_t)K * 2;

    auto stage = [&](int step, int buf) {        // 12 gload16 per thread
        size_t kb = (size_t)step * 128;          // 64 elems * 2B
#pragma unroll
        for (int i = 0; i < 4; i++) {            // A: 512 chunks of 16B
            int chunk = i * 128 + t;
            int row = chunk >> 3, c8 = chunk & 7;
            int csrc = c8 ^ (row & 7);
            gload16(Ab + (size_t)(m0 + row) * rs + kb + csrc * 16,
                    (char*)As[buf] + chunk * 16);
        }
#pragma unroll
        for (int i = 0; i < 8; i++) {            // B: 1024 chunks
            int chunk = i * 128 + t;
            int row = chunk >> 3, c8 = chunk & 7;
            int csrc = c8 ^ (row & 7);
            gload16(Bb + (size_t)(n0 + row) * rs + kb + csrc * 16,
                    (char*)Bs[buf] + chunk * 16);
        }
    };

    int nsteps = K >> 6;                         // 71
    stage(0, 0);
    if (nsteps > 1) stage(1, 1);
    for (int s = 0; s < nsteps; ++s) {
        int cur = s & 1;
        if (s + 1 < nsteps) { asm volatile("s_waitcnt vmcnt(12)" ::: "memory"); }
        else                { asm volatile("s_waitcnt vmcnt(0)" ::: "memory"); }
        __builtin_amdgcn_s_barrier();            // stage(s) fully landed (all waves)
        bf16x8 af[4][2], bfr[4][2];
#pragma unroll
        for (int mi = 0; mi < 4; mi++) {
            int row = mi * 16 + lr;
#pragma unroll
            for (int kk = 0; kk < 2; kk++)
                af[mi][kk] = as_bf(*(const u16x8*)&As[cur][row * 64 + (((kk * 4 + lg) ^ (row & 7)) << 3)]);
        }
#pragma unroll
        for (int ni = 0; ni < 4; ni++) {
            int row = wn * 64 + ni * 16 + lr;
#pragma unroll
            for (int kk = 0; kk < 2; kk++)
                bfr[ni][kk] = as_bf(*(const u16x8*)&Bs[cur][row * 64 + (((kk * 4 + lg) ^ (row & 7)) << 3)]);
        }
        asm volatile("s_waitcnt lgkmcnt(0)" ::: "memory");   // frags in regs
        __builtin_amdgcn_s_barrier();            // all waves done reading buf cur
        if (s + 2 < nsteps) stage(s + 2, cur);   // loads fly under the MFMAs
#pragma unroll
        for (int kk = 0; kk < 2; kk++)
#pragma unroll
            for (int mi = 0; mi < 4; mi++)
#pragma unroll
                for (int ni = 0; ni < 4; ni++)
                    acc[mi][ni] = __builtin_amdgcn_mfma_f32_16x16x32_bf16(
                        af[mi][kk], bfr[ni][kk], acc[mi][ni], 0, 0, 0);
    }

    if (EPI == 0) {
        float* C = (float*)Cout;
#pragma unroll
        for (int mi = 0; mi < 4; mi++)
#pragma unroll
            for (int ni = 0; ni < 4; ni++) {
                int col = n0 + wn * 64 + ni * 16 + lr;
                if (col < n_store) {
#pragma unroll
                    for (int i = 0; i < 4; i++) {
                        int row = m0 + mi * 16 + 4 * lg + i;
                        C[(size_t)row * ldc + col] = acc[mi][ni][i];
                    }
                }
            }
    } else {
        int hh = nb * 2 + wn;                 // head index (0..73)
        if (hh == 72) {                       // v: write transposed [d][1024]
#pragma unroll
            for (int mi = 0; mi < 4; mi++)
#pragma unroll
                for (int ni = 0; ni < 4; ni++) {
                    int d = ni * 16 + lr;
                    int s0 = m0 + mi * 16 + 4 * lg;
                    u16x4 pk;
#pragma unroll
                    for (int i = 0; i < 4; i++) pk[i] = f2bf(acc[mi][ni][i]);
                    *(u16x4*)&v_out[(size_t)d * S_LEN + s0] = pk;
                }
        } else if (hh < 72) {                 // q (hh<71) / k (hh==71): rope
            unsigned short* qb = (unsigned short*)Cout;
            float qscale = (hh < 71) ? 0.125f : 1.0f;
#pragma unroll
            for (int mi = 0; mi < 4; mi++)
#pragma unroll
                for (int i = 0; i < 4; i++) {
                    int s = m0 + mi * 16 + 4 * lg + i;
                    float c0 = cs_t[s * 32 + lr],      g0 = sn_t[s * 32 + lr];
                    float c1 = cs_t[s * 32 + 16 + lr], g1 = sn_t[s * 32 + 16 + lr];
#pragma unroll
                    for (int ni = 0; ni < 4; ni++) {
                        float x  = acc[mi][ni][i];
                        float xp = acc[mi][ni ^ 2][i];
                        float c = (ni & 1) ? c1 : c0;
                        float g = (ni & 1) ? g1 : g0;
                        float r = (ni < 2) ? (x * c - xp * g) : (x * c + xp * g);
                        r *= qscale;
                        int d = ni * 16 + lr;
                        if (hh < 71) qb[(size_t)s * HID + hh * 64 + d] = f2bf(r);
                        else         k_out[(size_t)s * 64 + d] = f2bf(r);
                    }
                }
        }                                     // hh == 73: padding, skip
    }
}

// ---------- flash attention (MQA) + fused dense cvt_wT tail ----------
// grid (40 + 72, 71). u < 40: attn block (head h, chunk c, 4 q-tiles).
// u >= 40: dense cvt tile idx = (u-40) + 72*h — rides attn's idle HBM BW
// (attn is latency-bound: MfmaUtil <5%, ~0.9 TB/s).
__global__ __launch_bounds__(256, 3) void attn_kernel(
        const unsigned short* __restrict__ qb, const unsigned short* __restrict__ kr,
        const unsigned short* __restrict__ vt, unsigned short* __restrict__ ctx,
        unsigned short* __restrict__ Opart, float2* __restrict__ MLpart,
        const float* __restrict__ w2, unsigned short* __restrict__ wt2) {
    __shared__ char smem[41984];
    unsigned short* Ks = (unsigned short*)smem;             // [2][64*64]
    unsigned short* Vs = (unsigned short*)(smem + 16384);   // [2][64*64]
    unsigned short* Pl = (unsigned short*)(smem + 32768);   // [4][16*72]
    int h = blockIdx.y;
    int u = blockIdx.x;
    int t = threadIdx.x;

    if (u >= 40) {
        // ---- dense cvt: [K][HID] fp32 -> [ND_PAD][K] bf16, 64x64 tile ----
        float (*tb)[65] = (float(*)[65])smem;
        int idx = (u - 40) + 72 * h;               // 0..5111
        int n0 = (idx % 72) * 64, k0 = (idx / 72) * 64;
        int tx = t & 15, ty = t >> 4;              // 16 x 16
#pragma unroll
        for (int r = 0; r < 64; r += 16) {
            int k = k0 + ty + r, n = n0 + tx * 4;
            float4 v = make_float4(0.f, 0.f, 0.f, 0.f);
            if (n < HID) v = *(const float4*)&w2[(size_t)k * HID + n];
            tb[ty + r][tx * 4 + 0] = v.x;
            tb[ty + r][tx * 4 + 1] = v.y;
            tb[ty + r][tx * 4 + 2] = v.z;
            tb[ty + r][tx * 4 + 3] = v.w;
        }
        __syncthreads();
        int nr = t >> 2, kq = (t & 3) * 16;
        unsigned short tmp[16];
#pragma unroll
        for (int z = 0; z < 16; z++) tmp[z] = f2bf(tb[kq + z][nr]);
        u16x8* dst = (u16x8*)&wt2[(size_t)(n0 + nr) * HID + k0 + kq];
        dst[0] = *(const u16x8*)&tmp[0];
        dst[1] = *(const u16x8*)&tmp[8];
        return;
    }

    int c, j0;
    if (u < 16)      { c = 0; j0 = u * 4; }
    else if (u < 28) { c = 1; j0 = 16 + (u - 16) * 4; }
    else if (u < 36) { c = 2; j0 = 32 + (u - 28) * 4; }
    else             { c = 3; j0 = 48 + (u - 36) * 4; }
    int wv = t >> 6, lane = t & 63, lr = lane & 15, lg = lane >> 4;
    int j = j0 + wv;
    int qs = j * 16 + lr;
    int k_lo = c * 256;
    int kend_w   = min((j + 1) * 16, k_lo + 256);
    int kend_max = min((j0 + 4) * 16, k_lo + 256);
    int nt = (kend_max - k_lo) >> 6;
    int nch = (j >> 4) + 1;
    int srow = t >> 3, sc16 = t & 7, sw = lr & 7;

    auto stage = [&](int ti, int buf) {          // 4 global_load_lds per thread
        size_t kbase = (size_t)(k_lo + ti * 64);
#pragma unroll
        for (int i = 0; i < 2; i++) {
            int row = i * 32 + srow;
            int csrc = sc16 ^ (row & 7);
            gload16((const char*)kr + (kbase + row) * 128 + csrc * 16,
                    (char*)Ks + buf * 8192 + (i * 256 + t) * 16);
        }
#pragma unroll
        for (int i = 0; i < 2; i++) {
            int row = i * 32 + srow;
            int csrc = sc16 ^ (row & 7);
            gload16((const char*)vt + (size_t)row * 2048 + kbase * 2 + csrc * 16,
                    (char*)Vs + buf * 8192 + (i * 256 + t) * 16);
        }
    };

    bf16x8 qf[2];
#pragma unroll
    for (int dc = 0; dc < 2; dc++)
        qf[dc] = as_bf(*(const u16x8*)&qb[(size_t)qs * HID + h * 64 + dc * 32 + 8 * lg]);

    float m_i = -1e30f, l_i = 0.0f;
    f32x4 o[4];
#pragma unroll
    for (int d4 = 0; d4 < 4; d4++) o[d4] = (f32x4)0.0f;

    stage(0, 0);
    if (nt > 1) stage(1, 1);

    for (int ti = 0; ti < nt; ti++) {
        int cur = ti & 1;
        if (ti + 1 < nt) { asm volatile("s_waitcnt vmcnt(4)" ::: "memory"); }
        else             { asm volatile("s_waitcnt vmcnt(0)" ::: "memory"); }
        __builtin_amdgcn_s_barrier();            // tile ti fully landed
        int k0 = k_lo + ti * 64;
        if (k0 < kend_w) {
            f32x4 st[4];
#pragma unroll
            for (int nc = 0; nc < 4; nc++) st[nc] = (f32x4)0.0f;
#pragma unroll
            for (int nc = 0; nc < 4; nc++) {
                int krow = nc * 16 + lr;
#pragma unroll
                for (int dc = 0; dc < 2; dc++) {
                    bf16x8 kf = as_bf(*(const u16x8*)&Ks[cur * 4096 + krow * 64 + (((dc * 4 + lg) ^ sw) << 3)]);
                    st[nc] = __builtin_amdgcn_mfma_f32_16x16x32_bf16(kf, qf[dc], st[nc], 0, 0, 0);
                }
            }
            bool needmask = (k0 + 64 > j * 16);
            float mx = -1e30f;
            if (needmask) {
#pragma unroll
                for (int nc = 0; nc < 4; nc++)
#pragma unroll
                    for (int i = 0; i < 4; i++) {
                        int ks = k0 + nc * 16 + 4 * lg + i;
                        float v = (ks <= qs) ? st[nc][i] : -1e30f;
                        st[nc][i] = v;
                        mx = fmaxf(mx, v);
                    }
            } else {
#pragma unroll
                for (int nc = 0; nc < 4; nc++)
#pragma unroll
                    for (int i = 0; i < 4; i++) mx = fmaxf(mx, st[nc][i]);
            }
            mx = fmaxf(mx, __shfl_xor(mx, 16));
            mx = fmaxf(mx, __shfl_xor(mx, 32));
            // T13 defer-max: skip rescale while max grows by <= 8
            if (!__all(mx <= m_i + 8.0f)) {
                float mn = fmaxf(m_i, mx);
                float so = __expf(m_i - mn);
                l_i *= so;
#pragma unroll
                for (int d4 = 0; d4 < 4; d4++)
#pragma unroll
                    for (int i = 0; i < 4; i++) o[d4][i] *= so;
                m_i = mn;
            }
            float ps = 0.0f;
#pragma unroll
            for (int nc = 0; nc < 4; nc++)
#pragma unroll
                for (int i = 0; i < 4; i++) {
                    float v = st[nc][i];
                    float e = (!needmask || v > -1e29f) ? __expf(v - m_i) : 0.0f;
                    st[nc][i] = e;
                    ps += e;
                }
            ps += __shfl_xor(ps, 16);
            ps += __shfl_xor(ps, 32);
            l_i += ps;
            // P^T (lane-local) -> Pl[q=lr][k] (pad 72: conflict-free)
#pragma unroll
            for (int nc = 0; nc < 4; nc++) {
                *(unsigned*)&Pl[wv * 1152 + lr * 72 + nc * 16 + 4 * lg]     = pk2(st[nc][0], st[nc][1]);
                *(unsigned*)&Pl[wv * 1152 + lr * 72 + nc * 16 + 4 * lg + 2] = pk2(st[nc][2], st[nc][3]);
            }
            bf16x8 pb[2];
#pragma unroll
            for (int kk = 0; kk < 2; kk++)
                pb[kk] = as_bf(*(const u16x8*)&Pl[wv * 1152 + lr * 72 + kk * 32 + 8 * lg]);
#pragma unroll
            for (int d4 = 0; d4 < 4; d4++) {
                int vrow = d4 * 16 + lr;
#pragma unroll
                for (int kk = 0; kk < 2; kk++) {
                    bf16x8 vf = as_bf(*(const u16x8*)&Vs[cur * 4096 + vrow * 64 + (((kk * 4 + lg) ^ sw) << 3)]);
                    o[d4] = __builtin_amdgcn_mfma_f32_16x16x32_bf16(vf, pb[kk], o[d4], 0, 0, 0);
                }
            }
        }
        __builtin_amdgcn_s_barrier();            // all waves consumed buf cur
        if (ti + 2 < nt) stage(ti + 2, cur);     // overwrite buf cur
    }

    if (nch == 1) {
        float linv = 1.0f / l_i;
#pragma unroll
        for (int d4 = 0; d4 < 4; d4++) {
            u16x4 pk;
#pragma unroll
            for (int i = 0; i < 4; i++) pk[i] = f2bf(o[d4][i] * linv);
            *(u16x4*)&ctx[(size_t)qs * HID + h * 64 + d4 * 16 + 4 * lg] = pk;
        }
    } else {
        int pi = (h * 48 + (j - 16)) * 4 + c;
#pragma unroll
        for (int d4 = 0; d4 < 4; d4++) {
            u16x4 pk;
#pragma unroll
            for (int i = 0; i < 4; i++) pk[i] = f2bf(o[d4][i]);
            *(u16x4*)&Opart[(size_t)pi * 1024 + lr * 64 + d4 * 16 + 4 * lg] = pk;
        }
        if (lg == 0) MLpart[pi * 16 + lr] = make_float2(m_i, l_i);
    }
}

// ---------- split-K merge: one wave per (h, j>=16) ----------
__global__ __launch_bounds__(256) void merge_kernel(
        const unsigned short* __restrict__ Opart, const float2* __restrict__ MLpart,
        unsigned short* __restrict__ ctx) {
    int mu = blockIdx.x * 4 + (threadIdx.x >> 6);
    int lane = threadIdx.x & 63;
    int h = mu / 48, jj = mu % 48, j = 16 + jj;
    int nch = (j >> 4) + 1;
    int base = (h * 48 + jj) * 4;
    for (int q = 0; q < 16; q++) {
        float m[4], l[4], w[4];
        float M = -1e30f;
        for (int c = 0; c < nch; c++) {
            float2 ml = MLpart[(base + c) * 16 + q];
            m[c] = ml.x; l[c] = ml.y;
            M = fmaxf(M, m[c]);
        }
        float L = 0.0f;
        for (int c = 0; c < nch; c++) { w[c] = __expf(m[c] - M); L += l[c] * w[c]; }
        float acc = 0.0f;
        for (int c = 0; c < nch; c++)
            acc += w[c] * bf2f(Opart[(size_t)(base + c) * 1024 + q * 64 + lane]);
        ctx[(size_t)(j * 16 + q) * HID + h * 64 + lane] = f2bf(acc / L);
    }
}

extern "C" void kernel_launch(void* const* d_in, const int* in_sizes, int n_in,
                              void* d_out, int out_size, void* d_ws, size_t ws_size,
                              hipStream_t stream) {
    const float* hs      = (const float*)d_in[0];
    // d_in[1] = attention_mask (analytic causal mask used instead)
    const float* qkv_w   = (const float*)d_in[2];
    const float* dense_w = (const float*)d_in[3];
    float* out = (float*)d_out;

    char* ws = (char*)d_ws;
    size_t off = 0;
    auto alloc = [&](size_t bytes) -> void* {
        void* p = ws + off;
        off += (bytes + 255) & ~(size_t)255;
        return p;
    };
    unsigned short* x_bf   = (unsigned short*)alloc((size_t)S_LEN * HID * 2);      // 9.3 MB
    unsigned short* wqkvT  = (unsigned short*)alloc((size_t)NQKV_PAD * HID * 2);   // 43.0 MB
    unsigned short* q_bf   = (unsigned short*)alloc((size_t)S_LEN * HID * 2);      // 9.3 MB
    unsigned short* k_rope = (unsigned short*)alloc((size_t)S_LEN * 64 * 2);
    unsigned short* v_t    = (unsigned short*)alloc((size_t)64 * S_LEN * 2);
    unsigned short* ctx    = (unsigned short*)alloc((size_t)S_LEN * HID * 2);      // 9.3 MB
    unsigned short* wdT    = (unsigned short*)alloc((size_t)ND_PAD * HID * 2);     // 41.9 MB
    float*          cs_t   = (float*)alloc((size_t)S_LEN * 32 * 4);
    float*          sn_t   = (float*)alloc((size_t)S_LEN * 32 * 4);
    (void)ws_size;   // ~113 MB
    // Opart/MLpart alias wqkvT (dead after QKV GEMM; attn/merge run later).
    // wdT is written by attn's fused cvt tail, read by dense GEMM (stream-ordered).
    unsigned short* Opart  = wqkvT;                                   // 27.9 MB
    float2*         MLpart = (float2*)((char*)wqkvT + (size_t)71 * 48 * 4 * 1024 * 2);

    // 1. fused prep: cvt_x | qkv cvt_wT | rope table
    prep_kernel<<<dim3(XB + WB + RB), dim3(256), 0, stream>>>(
        (const float4*)hs, (ushort4*)x_bf, qkv_w, wqkvT, cs_t, sn_t);

    // 2. QKV GEMM (592 = 8 XCD-chunks of 74) + fused extract/RoPE epilogue
    gemm_bt_kernel<1><<<dim3(16 * NQKV_PAD / 128), dim3(128), 0, stream>>>(
        x_bf, wqkvT, q_bf, cs_t, sn_t, k_rope, v_t, HID, HID, NQKV);

    // 3. attention + fused dense cvt_wT tail (72 extra u-blocks per head)
    attn_kernel<<<dim3(40 + 72, NH), dim3(256), 0, stream>>>(
        q_bf, k_rope, v_t, ctx, Opart, MLpart, dense_w, wdT);

    merge_kernel<<<dim3(NH * 48 / 4), dim3(256), 0, stream>>>(Opart, MLpart, ctx);

    // 4. dense GEMM (576 = 8 XCD-chunks of 72)
    gemm_bt_kernel<0><<<dim3(16 * ND_PAD / 128), dim3(128), 0, stream>>>(
        ctx, wdT, out, nullptr, nullptr, nullptr, nullptr, HID, HID, HID);
}